// Round 6
// baseline (313.897 us; speedup 1.0000x reference)
//
#include <hip/hip_runtime.h>

// Problem sizes (match reference)
#define NS0 300000
#define ND0 50000
#define NE0 800000
#define NS1 50000
#define ND1 8192
#define NE1 131072
#define IN_F 256
#define HID_F 128
#define SLOTS 64   // bucket-CSR capacity; indeg ~ Poisson(16), P(>=64) ~ 1e-19

// Workspace layout (4-byte words), all 16B-aligned:
//   outdeg0i [NS0]            @ 0
//   outdeg1i [NS1]            @ 300000
//   cnt0     [ND0]            @ 350000
//   cnt1     [ND1]            @ 400000     -- zeroed range ends 408192 (1.63 MB)
//   edge0    [ND0*SLOTS*2]    @ 408192     ends 6808192   (int2 per slot)
//   edge1    [ND1*SLOTS*2]    @ 6808192    ends 7856768
//   h1       [ND0*HID_F]      @ 7856768    ends 14256768
//   agg_lo   [ND0*128]        @ 14256768   ends 20656768  (82.6 MB total)
#define OFF_OUTDEG0I 0
#define OFF_OUTDEG1I 300000
#define OFF_CNT0     350000
#define OFF_CNT1     400000
#define ZERO_WORDS   408192
#define OFF_EDGE0    408192
#define OFF_EDGE1    6808192
#define OFF_H1       7856768
#define OFF_AGGLO    14256768

// ----------------------------------------------------------- zero counters
__global__ __launch_bounds__(256) void k_zero(int4* __restrict__ p, int n4) {
  int i = blockIdx.x * 256 + threadIdx.x;
  int s = gridDim.x * 256;
  for (; i < n4; i += s) p[i] = make_int4(0, 0, 0, 0);
}

// ------------------------------------------------- out-degree histograms only
__global__ __launch_bounds__(256) void k_hist(
    const int* __restrict__ src0, const int* __restrict__ src1,
    int* __restrict__ outdeg0, int* __restrict__ outdeg1) {
  int tid = blockIdx.x * blockDim.x + threadIdx.x;
  int stride = gridDim.x * blockDim.x;
  for (int i = tid; i < NE0; i += stride) atomicAdd(&outdeg0[src0[i]], 1);
  for (int i = tid; i < NE1; i += stride) atomicAdd(&outdeg1[src1[i]], 1);
}

// --------------------------------------- bucket-CSR scatter, both layers fused
// edge[d*SLOTS + slot] = (src, ew * rsqrt(max(outdeg[src],1)))
__global__ __launch_bounds__(256) void k_scatter(
    const int* __restrict__ src0, const int* __restrict__ dst0,
    const float* __restrict__ ew0, const int* __restrict__ outdeg0,
    int* __restrict__ cnt0, int2* __restrict__ edge0,
    const int* __restrict__ src1, const int* __restrict__ dst1,
    const float* __restrict__ ew1, const int* __restrict__ outdeg1,
    int* __restrict__ cnt1, int2* __restrict__ edge1) {
  int tid = blockIdx.x * blockDim.x + threadIdx.x;
  int stride = gridDim.x * blockDim.x;
  for (int i = tid; i < NE0; i += stride) {
    int s = src0[i];
    int d = dst0[i];
    float c = ew0[i] * rsqrtf(fmaxf((float)outdeg0[s], 1.0f));
    int slot = atomicAdd(&cnt0[d], 1);
    if (slot < SLOTS) edge0[d * SLOTS + slot] = make_int2(s, __float_as_int(c));
  }
  for (int i = tid; i < NE1; i += stride) {
    int s = src1[i];
    int d = dst1[i];
    float c = ew1[i] * rsqrtf(fmaxf((float)outdeg1[s], 1.0f));
    int slot = atomicAdd(&cnt1[d], 1);
    if (slot < SLOTS) edge1[d * SLOTS + slot] = make_int2(s, __float_as_int(c));
  }
}

#define FMA2(acc, c, v)        \
  acc.x = fmaf(c, v.x, acc.x); \
  acc.y = fmaf(c, v.y, acc.y);

// ------------------------------------- layer 1 pass A: gather dims [0, 128)
// Footprint x[:,0:128] = 153.6 MB -> L3-resident; reuse hits L3 not HBM.
// Block = 4 waves, 8 rows; wave owns 2 rows; lane holds float2 of 128 dims.
__global__ __launch_bounds__(256) void k_gather_lo(
    const float* __restrict__ x, const int* __restrict__ cnt,
    const int2* __restrict__ edge, float* __restrict__ agg_lo) {
  const int t = blockIdx.x;
  const int wv = threadIdx.x >> 6;
  const int lane = threadIdx.x & 63;
#pragma unroll
  for (int rr = 0; rr < 2; ++rr) {
    const int row = t * 8 + wv * 2 + rr;
    const int deg = min(cnt[row], SLOTS);
    const int2* ep = edge + (size_t)row * SLOTS;
    float2 acc = make_float2(0.f, 0.f);
    int e = 0;
    for (; e + 4 <= deg; e += 4) {
      int2 p0 = ep[e + 0], p1 = ep[e + 1], p2 = ep[e + 2], p3 = ep[e + 3];
      float2 v0 = *reinterpret_cast<const float2*>(x + (size_t)p0.x * IN_F + lane * 2);
      float2 v1 = *reinterpret_cast<const float2*>(x + (size_t)p1.x * IN_F + lane * 2);
      float2 v2 = *reinterpret_cast<const float2*>(x + (size_t)p2.x * IN_F + lane * 2);
      float2 v3 = *reinterpret_cast<const float2*>(x + (size_t)p3.x * IN_F + lane * 2);
      FMA2(acc, __int_as_float(p0.y), v0);
      FMA2(acc, __int_as_float(p1.y), v1);
      FMA2(acc, __int_as_float(p2.y), v2);
      FMA2(acc, __int_as_float(p3.y), v3);
    }
    for (; e < deg; ++e) {
      int2 p = ep[e];
      float2 v = *reinterpret_cast<const float2*>(x + (size_t)p.x * IN_F + lane * 2);
      FMA2(acc, __int_as_float(p.y), v);
    }
    const float sc = rsqrtf(fmaxf((float)deg, 1.0f));
    *reinterpret_cast<float2*>(agg_lo + (size_t)row * 128 + lane * 2) =
        make_float2(acc.x * sc, acc.y * sc);
  }
}

// ---------------- layer 1 pass B: gather dims [128, 256) + full 256-dim GEMM
__global__ __launch_bounds__(256) void k_layer1b(
    const float* __restrict__ x, const int* __restrict__ cnt,
    const int2* __restrict__ edge, const float* __restrict__ agg_lo,
    const float* __restrict__ W1, const float* __restrict__ b1,
    float* __restrict__ h1) {
  __shared__ float arow[8][IN_F];
  const int t = blockIdx.x;
  const int wv = threadIdx.x >> 6;
  const int lane = threadIdx.x & 63;

  // stage pass-A partials into LDS lo half (streamed, L3-hot)
  {
    const float4* srcv = reinterpret_cast<const float4*>(agg_lo + (size_t)t * 8 * 128);
    const int i = threadIdx.x;  // 256 float4 = 8 rows x 128 floats
    float4 v = srcv[i];
    const int r = i >> 5;           // /32 float4 per row
    const int c4 = i & 31;
    *reinterpret_cast<float4*>(&arow[r][c4 * 4]) = v;
  }

#pragma unroll
  for (int rr = 0; rr < 2; ++rr) {
    const int row = t * 8 + wv * 2 + rr;
    const int deg = min(cnt[row], SLOTS);
    const int2* ep = edge + (size_t)row * SLOTS;
    float2 acc = make_float2(0.f, 0.f);
    int e = 0;
    for (; e + 4 <= deg; e += 4) {
      int2 p0 = ep[e + 0], p1 = ep[e + 1], p2 = ep[e + 2], p3 = ep[e + 3];
      float2 v0 = *reinterpret_cast<const float2*>(x + (size_t)p0.x * IN_F + 128 + lane * 2);
      float2 v1 = *reinterpret_cast<const float2*>(x + (size_t)p1.x * IN_F + 128 + lane * 2);
      float2 v2 = *reinterpret_cast<const float2*>(x + (size_t)p2.x * IN_F + 128 + lane * 2);
      float2 v3 = *reinterpret_cast<const float2*>(x + (size_t)p3.x * IN_F + 128 + lane * 2);
      FMA2(acc, __int_as_float(p0.y), v0);
      FMA2(acc, __int_as_float(p1.y), v1);
      FMA2(acc, __int_as_float(p2.y), v2);
      FMA2(acc, __int_as_float(p3.y), v3);
    }
    for (; e < deg; ++e) {
      int2 p = ep[e];
      float2 v = *reinterpret_cast<const float2*>(x + (size_t)p.x * IN_F + 128 + lane * 2);
      FMA2(acc, __int_as_float(p.y), v);
    }
    const float sc = rsqrtf(fmaxf((float)deg, 1.0f));
    *reinterpret_cast<float2*>(&arow[wv * 2 + rr][128 + lane * 2]) =
        make_float2(acc.x * sc, acc.y * sc);
  }
  __syncthreads();

  const int j = threadIdx.x & 127;
  const int rg = threadIdx.x >> 7;  // rows rg*4 .. rg*4+3
  float a0 = 0.f, a1 = 0.f, a2 = 0.f, a3 = 0.f;
  const float* wj = W1 + j;
#pragma unroll 8
  for (int k = 0; k < IN_F; ++k) {
    const float wvv = wj[(size_t)k * 128];
    a0 = fmaf(arow[rg * 4 + 0][k], wvv, a0);
    a1 = fmaf(arow[rg * 4 + 1][k], wvv, a1);
    a2 = fmaf(arow[rg * 4 + 2][k], wvv, a2);
    a3 = fmaf(arow[rg * 4 + 3][k], wvv, a3);
  }
  const float bj = b1[j];
  const int row0 = t * 8 + rg * 4;
  h1[(size_t)(row0 + 0) * 128 + j] = fmaxf(a0 + bj, 0.0f);
  h1[(size_t)(row0 + 1) * 128 + j] = fmaxf(a1 + bj, 0.0f);
  h1[(size_t)(row0 + 2) * 128 + j] = fmaxf(a2 + bj, 0.0f);
  h1[(size_t)(row0 + 3) * 128 + j] = fmaxf(a3 + bj, 0.0f);
}

// --------------------------------------------- fused gather + GEMM, layer 2
// Source rows are h1 (25.6 MB, L3-resident); lane holds 2 dims; unroll 4.
__global__ __launch_bounds__(256) void k_layer2(
    const float* __restrict__ h1, const int* __restrict__ cnt,
    const int2* __restrict__ edge, const float* __restrict__ W2,
    const float* __restrict__ b2, float* __restrict__ out) {
  __shared__ float arow[8][HID_F];
  const int t = blockIdx.x;
  const int wv = threadIdx.x >> 6;
  const int lane = threadIdx.x & 63;

#pragma unroll
  for (int rr = 0; rr < 2; ++rr) {
    const int row = t * 8 + wv * 2 + rr;
    const int deg = min(cnt[row], SLOTS);
    const int2* ep = edge + (size_t)row * SLOTS;
    float2 acc = make_float2(0.f, 0.f);
    int e = 0;
    for (; e + 4 <= deg; e += 4) {
      int2 p0 = ep[e + 0], p1 = ep[e + 1], p2 = ep[e + 2], p3 = ep[e + 3];
      float2 v0 = *reinterpret_cast<const float2*>(h1 + (size_t)p0.x * HID_F + lane * 2);
      float2 v1 = *reinterpret_cast<const float2*>(h1 + (size_t)p1.x * HID_F + lane * 2);
      float2 v2 = *reinterpret_cast<const float2*>(h1 + (size_t)p2.x * HID_F + lane * 2);
      float2 v3 = *reinterpret_cast<const float2*>(h1 + (size_t)p3.x * HID_F + lane * 2);
      FMA2(acc, __int_as_float(p0.y), v0);
      FMA2(acc, __int_as_float(p1.y), v1);
      FMA2(acc, __int_as_float(p2.y), v2);
      FMA2(acc, __int_as_float(p3.y), v3);
    }
    for (; e < deg; ++e) {
      int2 p = ep[e];
      float2 v = *reinterpret_cast<const float2*>(h1 + (size_t)p.x * HID_F + lane * 2);
      FMA2(acc, __int_as_float(p.y), v);
    }
    const float sc = rsqrtf(fmaxf((float)deg, 1.0f));
    *reinterpret_cast<float2*>(&arow[wv * 2 + rr][lane * 2]) =
        make_float2(acc.x * sc, acc.y * sc);
  }
  __syncthreads();

  const int j = threadIdx.x & 127;
  const int rg = threadIdx.x >> 7;
  float a0 = 0.f, a1 = 0.f, a2 = 0.f, a3 = 0.f;
  const float* wj = W2 + j;
#pragma unroll 8
  for (int k = 0; k < HID_F; ++k) {
    const float wvv = wj[(size_t)k * 128];
    a0 = fmaf(arow[rg * 4 + 0][k], wvv, a0);
    a1 = fmaf(arow[rg * 4 + 1][k], wvv, a1);
    a2 = fmaf(arow[rg * 4 + 2][k], wvv, a2);
    a3 = fmaf(arow[rg * 4 + 3][k], wvv, a3);
  }
  const float bj = b2[j];
  const int row0 = t * 8 + rg * 4;
  out[(size_t)(row0 + 0) * 128 + j] = fmaxf(a0 + bj, 0.0f);
  out[(size_t)(row0 + 1) * 128 + j] = fmaxf(a1 + bj, 0.0f);
  out[(size_t)(row0 + 2) * 128 + j] = fmaxf(a2 + bj, 0.0f);
  out[(size_t)(row0 + 3) * 128 + j] = fmaxf(a3 + bj, 0.0f);
}

extern "C" void kernel_launch(void* const* d_in, const int* in_sizes, int n_in,
                              void* d_out, int out_size, void* d_ws, size_t ws_size,
                              hipStream_t stream) {
  const float* x    = (const float*)d_in[0];
  const int*   src0 = (const int*)d_in[1];
  const int*   dst0 = (const int*)d_in[2];
  const float* ew0  = (const float*)d_in[3];
  const int*   src1 = (const int*)d_in[4];
  const int*   dst1 = (const int*)d_in[5];
  const float* ew1  = (const float*)d_in[6];
  const float* W1   = (const float*)d_in[7];
  const float* b1   = (const float*)d_in[8];
  const float* W2   = (const float*)d_in[9];
  const float* b2   = (const float*)d_in[10];
  float* out = (float*)d_out;

  int*   wsi = (int*)d_ws;
  float* wsf = (float*)d_ws;
  int* outdeg0 = wsi + OFF_OUTDEG0I;
  int* outdeg1 = wsi + OFF_OUTDEG1I;
  int* cnt0    = wsi + OFF_CNT0;
  int* cnt1    = wsi + OFF_CNT1;
  int2* edge0  = (int2*)(wsi + OFF_EDGE0);
  int2* edge1  = (int2*)(wsi + OFF_EDGE1);
  float* h1    = wsf + OFF_H1;
  float* agglo = wsf + OFF_AGGLO;

  k_zero<<<128, 256, 0, stream>>>((int4*)d_ws, ZERO_WORDS / 4);
  k_hist<<<512, 256, 0, stream>>>(src0, src1, outdeg0, outdeg1);
  k_scatter<<<2048, 256, 0, stream>>>(src0, dst0, ew0, outdeg0, cnt0, edge0,
                                      src1, dst1, ew1, outdeg1, cnt1, edge1);
  // layer 1, feature-split two-pass gather (each pass L3-resident) + GEMM
  k_gather_lo<<<ND0 / 8, 256, 0, stream>>>(x, cnt0, edge0, agglo);
  k_layer1b<<<ND0 / 8, 256, 0, stream>>>(x, cnt0, edge0, agglo, W1, b1, h1);
  // layer 2
  k_layer2<<<ND1 / 8, 256, 0, stream>>>(h1, cnt1, edge1, W2, b2, out);
}

// Round 7
// 276.536 us; speedup vs baseline: 1.1351x; 1.1351x over previous
//
#include <hip/hip_runtime.h>

// Problem sizes (match reference)
#define NS0 300000
#define ND0 50000
#define NE0 800000
#define NS1 50000
#define ND1 8192
#define NE1 131072
#define IN_F 256
#define HID_F 128
#define SLOTS 64   // bucket-CSR capacity; indeg ~ Poisson(16), P(>=64) ~ 1e-19

// Workspace layout (4-byte words), all 16B-aligned:
//   outdeg0i [NS0]            @ 0
//   outdeg1i [NS1]            @ 300000
//   cnt0     [ND0]            @ 350000
//   cnt1     [ND1]            @ 400000     -- zeroed range ends 408192 (1.63 MB)
//   edge0    [ND0*SLOTS*2]    @ 408192     ends 6808192   (int2 (src, ew-bits))
//   edge1    [ND1*SLOTS*2]    @ 6808192    ends 7856768
//   h1       [ND0*HID_F]      @ 7856768    ends 14256768  (57 MB total)
#define OFF_OUTDEG0I 0
#define OFF_OUTDEG1I 300000
#define OFF_CNT0     350000
#define OFF_CNT1     400000
#define ZERO_WORDS   408192
#define OFF_EDGE0    408192
#define OFF_EDGE1    6808192
#define OFF_H1       7856768

// ----------------------------------------------------------- zero counters
__global__ __launch_bounds__(256) void k_zero(int4* __restrict__ p, int n4) {
  int i = blockIdx.x * 256 + threadIdx.x;
  int s = gridDim.x * 256;
  for (; i < n4; i += s) p[i] = make_int4(0, 0, 0, 0);
}

// ------------------- fused degree-histogram + bucket scatter (single pass)
// Bucket entry is (src, raw ew bits); the outdeg normalization is applied at
// gather time from the L2-resident outdeg array, removing the hist->scatter
// dependency and one full edge-list read.
__global__ __launch_bounds__(256) void k_build(
    const int* __restrict__ src0, const int* __restrict__ dst0,
    const float* __restrict__ ew0, int* __restrict__ outdeg0,
    int* __restrict__ cnt0, int2* __restrict__ edge0,
    const int* __restrict__ src1, const int* __restrict__ dst1,
    const float* __restrict__ ew1, int* __restrict__ outdeg1,
    int* __restrict__ cnt1, int2* __restrict__ edge1) {
  int tid = blockIdx.x * blockDim.x + threadIdx.x;
  int stride = gridDim.x * blockDim.x;
  for (int i = tid; i < NE0; i += stride) {
    int s = src0[i];
    int d = dst0[i];
    float w = ew0[i];
    atomicAdd(&outdeg0[s], 1);
    int slot = atomicAdd(&cnt0[d], 1);
    if (slot < SLOTS) edge0[d * SLOTS + slot] = make_int2(s, __float_as_int(w));
  }
  for (int i = tid; i < NE1; i += stride) {
    int s = src1[i];
    int d = dst1[i];
    float w = ew1[i];
    atomicAdd(&outdeg1[s], 1);
    int slot = atomicAdd(&cnt1[d], 1);
    if (slot < SLOTS) edge1[d * SLOTS + slot] = make_int2(s, __float_as_int(w));
  }
}

#define FMA4(acc, c, v)        \
  acc.x = fmaf(c, v.x, acc.x); \
  acc.y = fmaf(c, v.y, acc.y); \
  acc.z = fmaf(c, v.z, acc.z); \
  acc.w = fmaf(c, v.w, acc.w);

#define COEF(sr, wbits) \
  (__int_as_float(wbits) * rsqrtf(fmaxf((float)outdeg[sr], 1.0f)))

// --------------------------------------------- fused gather + GEMM, layer 1
// Block = 256 threads = 4 waves, tile of 8 dst rows (grid = ND0/8 exactly).
// Gather: wave w owns rows (8t+2w, 8t+2w+1); lane holds 4 of 256 dims.
// GEMM:   thread (j = tid&127, rg = tid>>7) does 4 rows x col j.
__global__ __launch_bounds__(256) void k_layer1(
    const float* __restrict__ x, const int* __restrict__ cnt,
    const int* __restrict__ outdeg, const int2* __restrict__ edge,
    const float* __restrict__ W1, const float* __restrict__ b1,
    float* __restrict__ h1) {
  __shared__ float arow[8][IN_F];
  const int t = blockIdx.x;
  const int wv = threadIdx.x >> 6;
  const int lane = threadIdx.x & 63;

#pragma unroll
  for (int rr = 0; rr < 2; ++rr) {
    const int row = t * 8 + wv * 2 + rr;
    const int deg = min(cnt[row], SLOTS);
    const int2* ep = edge + (size_t)row * SLOTS;
    float4 acc = make_float4(0.f, 0.f, 0.f, 0.f);
    int e = 0;
    for (; e + 4 <= deg; e += 4) {
      int4 q0 = *reinterpret_cast<const int4*>(ep + e);      // edges e, e+1
      int4 q1 = *reinterpret_cast<const int4*>(ep + e + 2);  // edges e+2, e+3
      float4 v0 = *reinterpret_cast<const float4*>(x + (size_t)q0.x * IN_F + lane * 4);
      float4 v1 = *reinterpret_cast<const float4*>(x + (size_t)q0.z * IN_F + lane * 4);
      float4 v2 = *reinterpret_cast<const float4*>(x + (size_t)q1.x * IN_F + lane * 4);
      float4 v3 = *reinterpret_cast<const float4*>(x + (size_t)q1.z * IN_F + lane * 4);
      float c0 = COEF(q0.x, q0.y);
      float c1 = COEF(q0.z, q0.w);
      float c2 = COEF(q1.x, q1.y);
      float c3 = COEF(q1.z, q1.w);
      FMA4(acc, c0, v0);
      FMA4(acc, c1, v1);
      FMA4(acc, c2, v2);
      FMA4(acc, c3, v3);
    }
    for (; e < deg; ++e) {
      int2 p = ep[e];
      float4 v = *reinterpret_cast<const float4*>(x + (size_t)p.x * IN_F + lane * 4);
      float c = COEF(p.x, p.y);
      FMA4(acc, c, v);
    }
    const float sc = rsqrtf(fmaxf((float)deg, 1.0f));
    *reinterpret_cast<float4*>(&arow[wv * 2 + rr][lane * 4]) =
        make_float4(acc.x * sc, acc.y * sc, acc.z * sc, acc.w * sc);
  }
  __syncthreads();

  const int j = threadIdx.x & 127;
  const int rg = threadIdx.x >> 7;  // rows rg*4 .. rg*4+3
  float a0 = 0.f, a1 = 0.f, a2 = 0.f, a3 = 0.f;
  const float* wj = W1 + j;
#pragma unroll 8
  for (int k = 0; k < IN_F; ++k) {
    const float wvv = wj[(size_t)k * 128];
    a0 = fmaf(arow[rg * 4 + 0][k], wvv, a0);
    a1 = fmaf(arow[rg * 4 + 1][k], wvv, a1);
    a2 = fmaf(arow[rg * 4 + 2][k], wvv, a2);
    a3 = fmaf(arow[rg * 4 + 3][k], wvv, a3);
  }
  const float bj = b1[j];
  const int row0 = t * 8 + rg * 4;
  h1[(size_t)(row0 + 0) * 128 + j] = fmaxf(a0 + bj, 0.0f);
  h1[(size_t)(row0 + 1) * 128 + j] = fmaxf(a1 + bj, 0.0f);
  h1[(size_t)(row0 + 2) * 128 + j] = fmaxf(a2 + bj, 0.0f);
  h1[(size_t)(row0 + 3) * 128 + j] = fmaxf(a3 + bj, 0.0f);
}

#define FMA2(acc, c, v)        \
  acc.x = fmaf(c, v.x, acc.x); \
  acc.y = fmaf(c, v.y, acc.y);

// --------------------------------------------- fused gather + GEMM, layer 2
// Source rows are h1 (25.6 MB, L3-resident); lane holds 2 dims.
__global__ __launch_bounds__(256) void k_layer2(
    const float* __restrict__ h1, const int* __restrict__ cnt,
    const int* __restrict__ outdeg, const int2* __restrict__ edge,
    const float* __restrict__ W2, const float* __restrict__ b2,
    float* __restrict__ out) {
  __shared__ float arow[8][HID_F];
  const int t = blockIdx.x;
  const int wv = threadIdx.x >> 6;
  const int lane = threadIdx.x & 63;

#pragma unroll
  for (int rr = 0; rr < 2; ++rr) {
    const int row = t * 8 + wv * 2 + rr;
    const int deg = min(cnt[row], SLOTS);
    const int2* ep = edge + (size_t)row * SLOTS;
    float2 acc = make_float2(0.f, 0.f);
    int e = 0;
    for (; e + 4 <= deg; e += 4) {
      int4 q0 = *reinterpret_cast<const int4*>(ep + e);
      int4 q1 = *reinterpret_cast<const int4*>(ep + e + 2);
      float2 v0 = *reinterpret_cast<const float2*>(h1 + (size_t)q0.x * HID_F + lane * 2);
      float2 v1 = *reinterpret_cast<const float2*>(h1 + (size_t)q0.z * HID_F + lane * 2);
      float2 v2 = *reinterpret_cast<const float2*>(h1 + (size_t)q1.x * HID_F + lane * 2);
      float2 v3 = *reinterpret_cast<const float2*>(h1 + (size_t)q1.z * HID_F + lane * 2);
      float c0 = COEF(q0.x, q0.y);
      float c1 = COEF(q0.z, q0.w);
      float c2 = COEF(q1.x, q1.y);
      float c3 = COEF(q1.z, q1.w);
      FMA2(acc, c0, v0);
      FMA2(acc, c1, v1);
      FMA2(acc, c2, v2);
      FMA2(acc, c3, v3);
    }
    for (; e < deg; ++e) {
      int2 p = ep[e];
      float2 v = *reinterpret_cast<const float2*>(h1 + (size_t)p.x * HID_F + lane * 2);
      float c = COEF(p.x, p.y);
      FMA2(acc, c, v);
    }
    const float sc = rsqrtf(fmaxf((float)deg, 1.0f));
    *reinterpret_cast<float2*>(&arow[wv * 2 + rr][lane * 2]) =
        make_float2(acc.x * sc, acc.y * sc);
  }
  __syncthreads();

  const int j = threadIdx.x & 127;
  const int rg = threadIdx.x >> 7;
  float a0 = 0.f, a1 = 0.f, a2 = 0.f, a3 = 0.f;
  const float* wj = W2 + j;
#pragma unroll 8
  for (int k = 0; k < HID_F; ++k) {
    const float wvv = wj[(size_t)k * 128];
    a0 = fmaf(arow[rg * 4 + 0][k], wvv, a0);
    a1 = fmaf(arow[rg * 4 + 1][k], wvv, a1);
    a2 = fmaf(arow[rg * 4 + 2][k], wvv, a2);
    a3 = fmaf(arow[rg * 4 + 3][k], wvv, a3);
  }
  const float bj = b2[j];
  const int row0 = t * 8 + rg * 4;
  out[(size_t)(row0 + 0) * 128 + j] = fmaxf(a0 + bj, 0.0f);
  out[(size_t)(row0 + 1) * 128 + j] = fmaxf(a1 + bj, 0.0f);
  out[(size_t)(row0 + 2) * 128 + j] = fmaxf(a2 + bj, 0.0f);
  out[(size_t)(row0 + 3) * 128 + j] = fmaxf(a3 + bj, 0.0f);
}

extern "C" void kernel_launch(void* const* d_in, const int* in_sizes, int n_in,
                              void* d_out, int out_size, void* d_ws, size_t ws_size,
                              hipStream_t stream) {
  const float* x    = (const float*)d_in[0];
  const int*   src0 = (const int*)d_in[1];
  const int*   dst0 = (const int*)d_in[2];
  const float* ew0  = (const float*)d_in[3];
  const int*   src1 = (const int*)d_in[4];
  const int*   dst1 = (const int*)d_in[5];
  const float* ew1  = (const float*)d_in[6];
  const float* W1   = (const float*)d_in[7];
  const float* b1   = (const float*)d_in[8];
  const float* W2   = (const float*)d_in[9];
  const float* b2   = (const float*)d_in[10];
  float* out = (float*)d_out;

  int*   wsi = (int*)d_ws;
  float* wsf = (float*)d_ws;
  int* outdeg0 = wsi + OFF_OUTDEG0I;
  int* outdeg1 = wsi + OFF_OUTDEG1I;
  int* cnt0    = wsi + OFF_CNT0;
  int* cnt1    = wsi + OFF_CNT1;
  int2* edge0  = (int2*)(wsi + OFF_EDGE0);
  int2* edge1  = (int2*)(wsi + OFF_EDGE1);
  float* h1    = wsf + OFF_H1;

  k_zero<<<128, 256, 0, stream>>>((int4*)d_ws, ZERO_WORDS / 4);
  k_build<<<1024, 256, 0, stream>>>(src0, dst0, ew0, outdeg0, cnt0, edge0,
                                    src1, dst1, ew1, outdeg1, cnt1, edge1);
  k_layer1<<<ND0 / 8, 256, 0, stream>>>(x, cnt0, outdeg0, edge0, W1, b1, h1);
  k_layer2<<<ND1 / 8, 256, 0, stream>>>(h1, cnt1, outdeg1, edge1, W2, b2, out);
}